// Round 4
// baseline (849.729 us; speedup 1.0000x reference)
//
#include <hip/hip_runtime.h>
#include <hip/hip_bf16.h>

#define DD 128

typedef __attribute__((ext_vector_type(8))) short short8;
typedef __attribute__((ext_vector_type(4))) float f32x4;

__device__ __forceinline__ float bf2f(short s) {
    union { unsigned u; float f; } c; c.u = ((unsigned)(unsigned short)s) << 16; return c.f;
}
__device__ __forceinline__ short f2bf(float f) {   // round-to-nearest-even
    union { float f; unsigned u; } c; c.f = f;
    unsigned u = c.u + 0x7fffu + ((c.u >> 16) & 1u);
    return (short)(u >> 16);
}

// ---------------------------------------------------------------------------
// x (fp32) -> bf16
// ---------------------------------------------------------------------------
__global__ __launch_bounds__(256) void f2b_k(
    const float* __restrict__ x, ushort* __restrict__ o, int n8)
{
    int i = blockIdx.x * 256 + threadIdx.x;
    if (i < n8) {
        float4 v0 = ((const float4*)x)[(size_t)i * 2];
        float4 v1 = ((const float4*)x)[(size_t)i * 2 + 1];
        short8 r;
        r[0] = f2bf(v0.x); r[1] = f2bf(v0.y); r[2] = f2bf(v0.z); r[3] = f2bf(v0.w);
        r[4] = f2bf(v1.x); r[5] = f2bf(v1.y); r[6] = f2bf(v1.z); r[7] = f2bf(v1.w);
        ((short8*)o)[i] = r;
    }
}

// ---------------------------------------------------------------------------
// Weights: W[k][n] fp32 -> Wt[n][k] bf16 (plain transpose, no swizzle —
// GEMMs read B-fragments directly from global/L2).
// mats 0-4: W1 layers, 5-9: W2 layers, 10: lin1_w. 11*16384 elements.
// ---------------------------------------------------------------------------
__global__ __launch_bounds__(256) void wconv_k(
    const float* __restrict__ W1, const float* __restrict__ W2,
    const float* __restrict__ L1, ushort* __restrict__ Wt)
{
    int idx = blockIdx.x * 256 + threadIdx.x;
    int mat = idx >> 14;
    if (mat >= 11) return;
    int e = idx & 16383;
    int k = e >> 7, n = e & 127;
    const float* src = (mat < 5) ? (W1 + (size_t)mat * 16384)
                     : (mat < 10) ? (W2 + (size_t)(mat - 5) * 16384) : L1;
    float v = src[e];                       // e = k*128+n (coalesced read)
    Wt[(size_t)mat * 16384 + n * 128 + k] = (ushort)f2bf(v);
}

// ---------------------------------------------------------------------------
// CSR build: histogram -> hierarchical exclusive scan -> fill
// ---------------------------------------------------------------------------
__global__ __launch_bounds__(256) void hist_k(
    const int* __restrict__ dst, int* __restrict__ cnt, int nEdges)
{
    int e0 = (blockIdx.x * 256 + threadIdx.x) * 4;
    if (e0 + 3 < nEdges) {
        int4 d = *(const int4*)(dst + e0);
        atomicAdd(&cnt[d.x], 1); atomicAdd(&cnt[d.y], 1);
        atomicAdd(&cnt[d.z], 1); atomicAdd(&cnt[d.w], 1);
    } else {
        for (int e = e0; e < nEdges; ++e) atomicAdd(&cnt[dst[e]], 1);
    }
}

__global__ __launch_bounds__(256) void reduce_k(
    const int* __restrict__ cnt, int* __restrict__ bsum, int n)
{
    __shared__ int s[256];
    int t = threadIdx.x;
    int base = blockIdx.x * 1024 + t * 4;
    int v = 0;
    if (base + 3 < n) { int4 c = *(const int4*)(cnt + base); v = c.x + c.y + c.z + c.w; }
    else { for (int i = 0; i < 4; ++i) if (base + i < n) v += cnt[base + i]; }
    s[t] = v; __syncthreads();
    for (int off = 128; off >= 1; off >>= 1) {
        if (t < off) s[t] += s[t + off];
        __syncthreads();
    }
    if (t == 0) bsum[blockIdx.x] = s[0];
}

__global__ __launch_bounds__(128) void scantop_k(
    int* __restrict__ bsum, int* __restrict__ totalOut, int nb)
{
    __shared__ int s[128];
    int t = threadIdx.x;
    int v = (t < nb) ? bsum[t] : 0;
    s[t] = v; __syncthreads();
    for (int off = 1; off < 128; off <<= 1) {
        int u = (t >= off) ? s[t - off] : 0;
        __syncthreads();
        s[t] += u;
        __syncthreads();
    }
    if (t < nb) bsum[t] = s[t] - v;       // exclusive
    if (t == 127) totalOut[0] = s[127];   // rowptr[N]
}

__global__ __launch_bounds__(256) void scanapply_k(
    const int* __restrict__ cnt, const int* __restrict__ bsum,
    int* __restrict__ rowptr, int* __restrict__ cursor, int n)
{
    __shared__ int s[256];
    int t = threadIdx.x;
    int base = blockIdx.x * 1024 + t * 4;
    int c[4]; int v = 0;
    for (int i = 0; i < 4; ++i) { c[i] = (base + i < n) ? cnt[base + i] : 0; v += c[i]; }
    s[t] = v; __syncthreads();
    int mine = v;
    for (int off = 1; off < 256; off <<= 1) {
        int u = (t >= off) ? s[t - off] : 0;
        __syncthreads();
        s[t] += u;
        __syncthreads();
    }
    int run = bsum[blockIdx.x] + s[t] - mine;
    for (int i = 0; i < 4; ++i) {
        if (base + i < n) { rowptr[base + i] = run; cursor[base + i] = run; run += c[i]; }
    }
}

__global__ __launch_bounds__(256) void fill_k(
    const int* __restrict__ src, const int* __restrict__ dst,
    int* __restrict__ cursor, int* __restrict__ csr, int nEdges)
{
    int e0 = (blockIdx.x * 256 + threadIdx.x) * 4;
    if (e0 + 3 < nEdges) {
        int4 d = *(const int4*)(dst + e0);
        int4 s = *(const int4*)(src + e0);
        csr[atomicAdd(&cursor[d.x], 1)] = s.x;
        csr[atomicAdd(&cursor[d.y], 1)] = s.y;
        csr[atomicAdd(&cursor[d.z], 1)] = s.z;
        csr[atomicAdd(&cursor[d.w], 1)] = s.w;
    } else {
        for (int e = e0; e < nEdges; ++e)
            csr[atomicAdd(&cursor[dst[e]], 1)] = src[e];
    }
}

// ---------------------------------------------------------------------------
// gather (bf16): out[i] = h[i] + sum_{k} h[csr[k]]   (fp32 accumulate)
//   16 lanes per node (16B each), 16 nodes per 256-thread block.
//   4-edge unroll for ILP (4 outstanding 16B loads per lane).
// ---------------------------------------------------------------------------
__global__ __launch_bounds__(256) void gather_bf_k(
    const ushort* __restrict__ h, const int* __restrict__ rowptr,
    const int* __restrict__ csr, ushort* __restrict__ out, int n)
{
    int node = blockIdx.x * 16 + (threadIdx.x >> 4);
    int j = threadIdx.x & 15;
    if (node >= n) return;
    int beg = rowptr[node], end = rowptr[node + 1];
    const short8* hp = (const short8*)h;

    float a[8];
    short8 v = hp[(size_t)node * 16 + j];
#pragma unroll
    for (int i = 0; i < 8; ++i) a[i] = bf2f(v[i]);

    int k = beg;
    for (; k + 3 < end; k += 4) {
        int s0 = csr[k], s1 = csr[k + 1], s2 = csr[k + 2], s3 = csr[k + 3];
        short8 v0 = hp[(size_t)s0 * 16 + j];
        short8 v1 = hp[(size_t)s1 * 16 + j];
        short8 v2 = hp[(size_t)s2 * 16 + j];
        short8 v3 = hp[(size_t)s3 * 16 + j];
#pragma unroll
        for (int i = 0; i < 8; ++i)
            a[i] += (bf2f(v0[i]) + bf2f(v1[i])) + (bf2f(v2[i]) + bf2f(v3[i]));
    }
    for (; k < end; ++k) {
        int s0 = csr[k];
        short8 v0 = hp[(size_t)s0 * 16 + j];
#pragma unroll
        for (int i = 0; i < 8; ++i) a[i] += bf2f(v0[i]);
    }
    short8 r;
#pragma unroll
    for (int i = 0; i < 8; ++i) r[i] = f2bf(a[i]);
    ((short8*)out)[(size_t)node * 16 + j] = r;
}

// ---------------------------------------------------------------------------
// Fused layer: O = relu( relu(BN(A@W1+b1)) @ W2 + b2 )       (TWO=true)
//          or: O = relu( epi(A@W1+b1) )                       (TWO=false)
// A bf16 [nrows][128]. W1t/W2t are transposed bf16 [n][k] in global (L2-hot),
// read directly as B-fragments (no LDS staging for W).
// LDS: one 32KB tile, XOR-swizzled (byte ^= (row&7)<<4). After the single
// staging barrier, each wave touches only its own 32 rows -> GEMM1-read,
// z-write, GEMM2-read need no further barriers (same-wave lgkmcnt ordering).
// mfma_f32_16x16x32_bf16; C/D: col=lane&15, row=(lane>>4)*4+reg  [m89/m91].
// ---------------------------------------------------------------------------
template <bool BN, bool TWO>
__global__ __launch_bounds__(256, 2) void layer_k(
    const ushort* __restrict__ A, const ushort* __restrict__ W1t,
    const float* __restrict__ bias1,
    const float* __restrict__ gamma, const float* __restrict__ beta,
    const float* __restrict__ mean, const float* __restrict__ var,
    const ushort* __restrict__ W2t, const float* __restrict__ bias2,
    ushort* __restrict__ O, int nrows)
{
    __shared__ ushort sA[16384];
    const int tid  = threadIdx.x;
    const int row0 = blockIdx.x * 128;

    // stage A with swizzle
#pragma unroll
    for (int i = 0; i < 8; ++i) {
        int f  = i * 256 + tid;     // 16B chunk id (2048 per tile)
        int r  = f >> 4;
        int c8 = f & 15;
        int gr = row0 + r;
        short8 v = {0, 0, 0, 0, 0, 0, 0, 0};
        if (gr < nrows) v = *(const short8*)(A + (size_t)gr * DD + c8 * 8);
        int db = (r * 256 + c8 * 16) ^ ((r & 7) << 4);
        *(short8*)((char*)sA + db) = v;
    }
    __syncthreads();

    const int lane = tid & 63;
    const int wv   = tid >> 6;
    const int m0   = wv * 32;
    const int lr   = lane & 15;
    const int lg   = lane >> 4;

    // epilogue-1 constants per col-frag: n = cf*16 + lr
    float mul8[8], add8[8];
#pragma unroll
    for (int cf = 0; cf < 8; ++cf) {
        int n = cf * 16 + lr;
        if (BN) {
            float s = gamma[n] * rsqrtf(var[n] + 1e-5f);
            mul8[cf] = s;
            add8[cf] = (bias1[n] - mean[n]) * s + beta[n];
        } else {
            mul8[cf] = 1.f;
            add8[cf] = bias1[n];
        }
    }

    f32x4 acc[2][8];
#pragma unroll
    for (int rf = 0; rf < 2; ++rf)
#pragma unroll
        for (int cf = 0; cf < 8; ++cf) acc[rf][cf] = (f32x4){0.f, 0.f, 0.f, 0.f};

    // ---- GEMM1: A @ W1 ----
#pragma unroll
    for (int kk = 0; kk < 4; ++kk) {
        const int kb = kk * 64 + lg * 16;          // byte offset of k-slice
        int ra0 = m0 + lr;
        int ra1 = m0 + 16 + lr;
        short8 a0 = *(short8*)((char*)sA + ((ra0 * 256 + kb) ^ ((ra0 & 7) << 4)));
        short8 a1 = *(short8*)((char*)sA + ((ra1 * 256 + kb) ^ ((ra1 & 7) << 4)));
        short8 b[8];
#pragma unroll
        for (int cf = 0; cf < 8; ++cf)
            b[cf] = *(const short8*)(W1t + (cf * 16 + lr) * 128 + kk * 32 + lg * 8);
#pragma unroll
        for (int cf = 0; cf < 8; ++cf) {
            acc[0][cf] = __builtin_amdgcn_mfma_f32_16x16x32_bf16(a0, b[cf], acc[0][cf], 0, 0, 0);
            acc[1][cf] = __builtin_amdgcn_mfma_f32_16x16x32_bf16(a1, b[cf], acc[1][cf], 0, 0, 0);
        }
    }

    if (!TWO) {
        // store epilogue-1 result
#pragma unroll
        for (int rf = 0; rf < 2; ++rf)
#pragma unroll
            for (int cf = 0; cf < 8; ++cf) {
                int n = cf * 16 + lr;
#pragma unroll
                for (int i = 0; i < 4; ++i) {
                    int m = row0 + m0 + rf * 16 + lg * 4 + i;
                    if (m < nrows) {
                        float vv = fmaxf(fmaf(acc[rf][cf][i], mul8[cf], add8[cf]), 0.f);
                        O[(size_t)m * DD + n] = (ushort)f2bf(vv);
                    }
                }
            }
        return;
    }

    // ---- epilogue-1 -> z (bf16) back into this wave's rows of sA ----
#pragma unroll
    for (int rf = 0; rf < 2; ++rf)
#pragma unroll
        for (int cf = 0; cf < 8; ++cf) {
            int n = cf * 16 + lr;
#pragma unroll
            for (int i = 0; i < 4; ++i) {
                int row = m0 + rf * 16 + lg * 4 + i;
                float vv = fmaxf(fmaf(acc[rf][cf][i], mul8[cf], add8[cf]), 0.f);
                int db = (row * 256 + n * 2) ^ ((row & 7) << 4);
                *(ushort*)((char*)sA + db) = (ushort)f2bf(vv);
            }
        }

    // ---- GEMM2: z @ W2 (z's feature axis is the contraction axis ->
    //      identical swizzled A-frag reads) ----
    f32x4 acc2[2][8];
#pragma unroll
    for (int rf = 0; rf < 2; ++rf)
#pragma unroll
        for (int cf = 0; cf < 8; ++cf) acc2[rf][cf] = (f32x4){0.f, 0.f, 0.f, 0.f};

#pragma unroll
    for (int kk = 0; kk < 4; ++kk) {
        const int kb = kk * 64 + lg * 16;
        int ra0 = m0 + lr;
        int ra1 = m0 + 16 + lr;
        short8 a0 = *(short8*)((char*)sA + ((ra0 * 256 + kb) ^ ((ra0 & 7) << 4)));
        short8 a1 = *(short8*)((char*)sA + ((ra1 * 256 + kb) ^ ((ra1 & 7) << 4)));
        short8 b[8];
#pragma unroll
        for (int cf = 0; cf < 8; ++cf)
            b[cf] = *(const short8*)(W2t + (cf * 16 + lr) * 128 + kk * 32 + lg * 8);
#pragma unroll
        for (int cf = 0; cf < 8; ++cf) {
            acc2[0][cf] = __builtin_amdgcn_mfma_f32_16x16x32_bf16(a0, b[cf], acc2[0][cf], 0, 0, 0);
            acc2[1][cf] = __builtin_amdgcn_mfma_f32_16x16x32_bf16(a1, b[cf], acc2[1][cf], 0, 0, 0);
        }
    }

    // ---- epilogue-2: bias + relu, bf16 store ----
    float add2[8];
#pragma unroll
    for (int cf = 0; cf < 8; ++cf) add2[cf] = bias2[cf * 16 + lr];
#pragma unroll
    for (int rf = 0; rf < 2; ++rf)
#pragma unroll
        for (int cf = 0; cf < 8; ++cf) {
            int n = cf * 16 + lr;
#pragma unroll
            for (int i = 0; i < 4; ++i) {
                int m = row0 + m0 + rf * 16 + lg * 4 + i;
                if (m < nrows) {
                    float vv = fmaxf(acc2[rf][cf][i] + add2[cf], 0.f);
                    O[(size_t)m * DD + n] = (ushort)f2bf(vv);
                }
            }
        }
}

// ---------------------------------------------------------------------------
// lin2 (128 -> 10) + log_softmax, bf16 input. One wave per row.
// ---------------------------------------------------------------------------
__global__ __launch_bounds__(256) void lin2_lsm_k(
    const ushort* __restrict__ in, const float* __restrict__ w,
    const float* __restrict__ b, float* __restrict__ out, int n)
{
    int tid  = threadIdx.x;
    int lane = tid & 63;
    int row  = blockIdx.x * 4 + (tid >> 6);
    if (row >= n) return;

    const ushort* hr = in + (size_t)row * DD;
    float x0 = bf2f((short)hr[lane]);
    float x1 = bf2f((short)hr[lane + 64]);

    float p[10];
#pragma unroll
    for (int c = 0; c < 10; ++c)
        p[c] = fmaf(x0, w[lane * 10 + c], x1 * w[(lane + 64) * 10 + c]);

#pragma unroll
    for (int off = 32; off >= 1; off >>= 1) {
#pragma unroll
        for (int c = 0; c < 10; ++c) p[c] += __shfl_xor(p[c], off, 64);
    }
#pragma unroll
    for (int c = 0; c < 10; ++c) p[c] += b[c];

    float m = p[0];
#pragma unroll
    for (int c = 1; c < 10; ++c) m = fmaxf(m, p[c]);
    float s = 0.f;
#pragma unroll
    for (int c = 0; c < 10; ++c) s += expf(p[c] - m);
    float lse = m + logf(s);

    if (lane < 10) out[(size_t)row * 10 + lane] = p[lane] - lse;
}

// ---------------------------------------------------------------------------

extern "C" void kernel_launch(void* const* d_in, const int* in_sizes, int n_in,
                              void* d_out, int out_size, void* d_ws, size_t ws_size,
                              hipStream_t stream)
{
    const float* x      = (const float*)d_in[0];
    const int*   ei     = (const int*)d_in[1];
    const float* W1     = (const float*)d_in[2];
    const float* b1     = (const float*)d_in[3];
    const float* gamma  = (const float*)d_in[4];
    const float* beta   = (const float*)d_in[5];
    const float* mean   = (const float*)d_in[6];
    const float* var    = (const float*)d_in[7];
    const float* W2     = (const float*)d_in[8];
    const float* b2     = (const float*)d_in[9];
    const float* lin1_w = (const float*)d_in[10];
    const float* lin1_b = (const float*)d_in[11];
    const float* lin2_w = (const float*)d_in[12];
    const float* lin2_b = (const float*)d_in[13];

    const int N = in_sizes[0] / DD;
    const int E = in_sizes[1] / 2;
    const int* srcI = ei;
    const int* dstI = ei + E;

    // workspace layout (all 16B-aligned)
    ushort* hb     = (ushort*)d_ws;                 // N*128 bf16
    ushort* gb     = hb + (size_t)N * DD;           // N*128 bf16
    ushort* Wt     = gb + (size_t)N * DD;           // 11*16384 bf16 (transposed)
    int*    rowptr = (int*)(Wt + 11 * 16384);       // N+4 ints
    int*    cnt    = rowptr + (N + 4);              // N ints (also cursor)
    int*    csr    = cnt + N;                       // E ints
    int*    bsum   = csr + E;                       // 128 ints

    const int nb       = (N + 1023) / 1024;
    const int gemmGrid = (N + 127) / 128;
    const int quadGrid = ((E + 3) / 4 + 255) / 256;

    // prep: bf16 conversions
    f2b_k<<<(N * DD / 8 + 255) / 256, 256, 0, stream>>>(x, hb, N * DD / 8);
    wconv_k<<<704, 256, 0, stream>>>(W1, W2, lin1_w, Wt);

    // CSR build
    hipMemsetAsync(cnt, 0, (size_t)N * sizeof(int), stream);
    hist_k<<<quadGrid, 256, 0, stream>>>(dstI, cnt, E);
    reduce_k<<<nb, 256, 0, stream>>>(cnt, bsum, N);
    scantop_k<<<1, 128, 0, stream>>>(bsum, rowptr + N, nb);
    scanapply_k<<<nb, 256, 0, stream>>>(cnt, bsum, rowptr, cnt, N);
    fill_k<<<quadGrid, 256, 0, stream>>>(srcI, dstI, cnt, csr, E);

    // layers: gather(hb->gb), fused layer (gb->hb)
    for (int l = 0; l < 5; ++l) {
        gather_bf_k<<<(N + 15) / 16, 256, 0, stream>>>(hb, rowptr, csr, gb, N);
        layer_k<true, true><<<gemmGrid, 256, 0, stream>>>(
            gb, Wt + (size_t)l * 16384, b1 + (size_t)l * DD,
            gamma + (size_t)l * DD, beta + (size_t)l * DD,
            mean + (size_t)l * DD, var + (size_t)l * DD,
            Wt + (size_t)(5 + l) * 16384, b2 + (size_t)l * DD, hb, N);
    }
    // lin1: hb -> gb
    layer_k<false, false><<<gemmGrid, 256, 0, stream>>>(
        hb, Wt + (size_t)10 * 16384, lin1_b,
        nullptr, nullptr, nullptr, nullptr, nullptr, nullptr, gb, N);
    // lin2 + log_softmax
    lin2_lsm_k<<<(N + 3) / 4, 256, 0, stream>>>(gb, lin2_w, lin2_b, (float*)d_out, N);
}

// Round 5
// 736.827 us; speedup vs baseline: 1.1532x; 1.1532x over previous
//
#include <hip/hip_runtime.h>
#include <hip/hip_bf16.h>

#define DD 128

typedef __attribute__((ext_vector_type(8))) short short8;
typedef __attribute__((ext_vector_type(4))) float f32x4;

__device__ __forceinline__ float bf2f(short s) {
    union { unsigned u; float f; } c; c.u = ((unsigned)(unsigned short)s) << 16; return c.f;
}
__device__ __forceinline__ short f2bf(float f) {   // round-to-nearest-even
    union { float f; unsigned u; } c; c.f = f;
    unsigned u = c.u + 0x7fffu + ((c.u >> 16) & 1u);
    return (short)(u >> 16);
}

// ---------------------------------------------------------------------------
// x (fp32) -> bf16
// ---------------------------------------------------------------------------
__global__ __launch_bounds__(256) void f2b_k(
    const float* __restrict__ x, ushort* __restrict__ o, int n8)
{
    int i = blockIdx.x * 256 + threadIdx.x;
    if (i < n8) {
        float4 v0 = ((const float4*)x)[(size_t)i * 2];
        float4 v1 = ((const float4*)x)[(size_t)i * 2 + 1];
        short8 r;
        r[0] = f2bf(v0.x); r[1] = f2bf(v0.y); r[2] = f2bf(v0.z); r[3] = f2bf(v0.w);
        r[4] = f2bf(v1.x); r[5] = f2bf(v1.y); r[6] = f2bf(v1.z); r[7] = f2bf(v1.w);
        ((short8*)o)[i] = r;
    }
}

// ---------------------------------------------------------------------------
// Weights: W[k][n] fp32 -> Wt[n][k] bf16, XOR-swizzled (ushort idx ^= (n&7)<<3)
// so LDS staging is a linear copy and LDS reads use byte ^ ((n&7)<<4).
// mats 0-4: W1 layers, 5-9: W2 layers, 10: lin1_w. 11*16384 elements.
// ---------------------------------------------------------------------------
__global__ __launch_bounds__(256) void wconv_k(
    const float* __restrict__ W1, const float* __restrict__ W2,
    const float* __restrict__ L1, ushort* __restrict__ Wt)
{
    int idx = blockIdx.x * 256 + threadIdx.x;
    int mat = idx >> 14;
    if (mat >= 11) return;
    int e = idx & 16383;
    int k = e >> 7, n = e & 127;
    const float* src = (mat < 5) ? (W1 + (size_t)mat * 16384)
                     : (mat < 10) ? (W2 + (size_t)(mat - 5) * 16384) : L1;
    float v = src[e];                       // e = k*128+n (coalesced read)
    int di = (n * 128 + k) ^ ((n & 7) << 3);
    Wt[(size_t)mat * 16384 + di] = (ushort)f2bf(v);
}

// ---------------------------------------------------------------------------
// CSR build: histogram -> hierarchical exclusive scan -> fill
// ---------------------------------------------------------------------------
__global__ __launch_bounds__(256) void hist_k(
    const int* __restrict__ dst, int* __restrict__ cnt, int nEdges)
{
    int e0 = (blockIdx.x * 256 + threadIdx.x) * 4;
    if (e0 + 3 < nEdges) {
        int4 d = *(const int4*)(dst + e0);
        atomicAdd(&cnt[d.x], 1); atomicAdd(&cnt[d.y], 1);
        atomicAdd(&cnt[d.z], 1); atomicAdd(&cnt[d.w], 1);
    } else {
        for (int e = e0; e < nEdges; ++e) atomicAdd(&cnt[dst[e]], 1);
    }
}

__global__ __launch_bounds__(256) void reduce_k(
    const int* __restrict__ cnt, int* __restrict__ bsum, int n)
{
    __shared__ int s[256];
    int t = threadIdx.x;
    int base = blockIdx.x * 1024 + t * 4;
    int v = 0;
    if (base + 3 < n) { int4 c = *(const int4*)(cnt + base); v = c.x + c.y + c.z + c.w; }
    else { for (int i = 0; i < 4; ++i) if (base + i < n) v += cnt[base + i]; }
    s[t] = v; __syncthreads();
    for (int off = 128; off >= 1; off >>= 1) {
        if (t < off) s[t] += s[t + off];
        __syncthreads();
    }
    if (t == 0) bsum[blockIdx.x] = s[0];
}

__global__ __launch_bounds__(128) void scantop_k(
    int* __restrict__ bsum, int* __restrict__ totalOut, int nb)
{
    __shared__ int s[128];
    int t = threadIdx.x;
    int v = (t < nb) ? bsum[t] : 0;
    s[t] = v; __syncthreads();
    for (int off = 1; off < 128; off <<= 1) {
        int u = (t >= off) ? s[t - off] : 0;
        __syncthreads();
        s[t] += u;
        __syncthreads();
    }
    if (t < nb) bsum[t] = s[t] - v;       // exclusive
    if (t == 127) totalOut[0] = s[127];   // rowptr[N]
}

__global__ __launch_bounds__(256) void scanapply_k(
    const int* __restrict__ cnt, const int* __restrict__ bsum,
    int* __restrict__ rowptr, int* __restrict__ cursor, int n)
{
    __shared__ int s[256];
    int t = threadIdx.x;
    int base = blockIdx.x * 1024 + t * 4;
    int c[4]; int v = 0;
    for (int i = 0; i < 4; ++i) { c[i] = (base + i < n) ? cnt[base + i] : 0; v += c[i]; }
    s[t] = v; __syncthreads();
    int mine = v;
    for (int off = 1; off < 256; off <<= 1) {
        int u = (t >= off) ? s[t - off] : 0;
        __syncthreads();
        s[t] += u;
        __syncthreads();
    }
    int run = bsum[blockIdx.x] + s[t] - mine;
    for (int i = 0; i < 4; ++i) {
        if (base + i < n) { rowptr[base + i] = run; cursor[base + i] = run; run += c[i]; }
    }
}

__global__ __launch_bounds__(256) void fill_k(
    const int* __restrict__ src, const int* __restrict__ dst,
    int* __restrict__ cursor, int* __restrict__ csr, int nEdges)
{
    int e0 = (blockIdx.x * 256 + threadIdx.x) * 4;
    if (e0 + 3 < nEdges) {
        int4 d = *(const int4*)(dst + e0);
        int4 s = *(const int4*)(src + e0);
        csr[atomicAdd(&cursor[d.x], 1)] = s.x;
        csr[atomicAdd(&cursor[d.y], 1)] = s.y;
        csr[atomicAdd(&cursor[d.z], 1)] = s.z;
        csr[atomicAdd(&cursor[d.w], 1)] = s.w;
    } else {
        for (int e = e0; e < nEdges; ++e)
            csr[atomicAdd(&cursor[dst[e]], 1)] = src[e];
    }
}

// ---------------------------------------------------------------------------
// gather (bf16): out[i] = h[i] + sum_{k} h[csr[k]]   (fp32 accumulate)
//   16 lanes per node (16B each), 16 nodes per 256-thread block.
//   4-edge unroll for ILP (4 outstanding 16B loads per lane).
// ---------------------------------------------------------------------------
__global__ __launch_bounds__(256) void gather_bf_k(
    const ushort* __restrict__ h, const int* __restrict__ rowptr,
    const int* __restrict__ csr, ushort* __restrict__ out, int n)
{
    int node = blockIdx.x * 16 + (threadIdx.x >> 4);
    int j = threadIdx.x & 15;
    if (node >= n) return;
    int beg = rowptr[node], end = rowptr[node + 1];
    const short8* hp = (const short8*)h;

    float a[8];
    short8 v = hp[(size_t)node * 16 + j];
#pragma unroll
    for (int i = 0; i < 8; ++i) a[i] = bf2f(v[i]);

    int k = beg;
    for (; k + 3 < end; k += 4) {
        int s0 = csr[k], s1 = csr[k + 1], s2 = csr[k + 2], s3 = csr[k + 3];
        short8 v0 = hp[(size_t)s0 * 16 + j];
        short8 v1 = hp[(size_t)s1 * 16 + j];
        short8 v2 = hp[(size_t)s2 * 16 + j];
        short8 v3 = hp[(size_t)s3 * 16 + j];
#pragma unroll
        for (int i = 0; i < 8; ++i)
            a[i] += (bf2f(v0[i]) + bf2f(v1[i])) + (bf2f(v2[i]) + bf2f(v3[i]));
    }
    for (; k < end; ++k) {
        int s0 = csr[k];
        short8 v0 = hp[(size_t)s0 * 16 + j];
#pragma unroll
        for (int i = 0; i < 8; ++i) a[i] += bf2f(v0[i]);
    }
    short8 r;
#pragma unroll
    for (int i = 0; i < 8; ++i) r[i] = f2bf(a[i]);
    ((short8*)out)[(size_t)node * 16 + j] = r;
}

// ---------------------------------------------------------------------------
// Fused layer: O = relu( relu(BN(A@W1+b1)) @ W2 + b2 )       (TWO=true)
//          or: O = relu( epi(A@W1+b1) )                       (TWO=false)
// A bf16 [nrows][128]. W1t/W2t are transposed+pre-swizzled bf16 in global.
// LDS: sA 32KB (input tile, XOR-swizzled byte^=(row&7)<<4) + sW 32KB.
// W2 is fetched into registers at kernel entry (T14 async-stage: latency
// hides under staging+GEMM1), ds_written over sW after GEMM1.
// z (epilogue-1 output) is written back into this wave's own 32 rows of sA,
// so GEMM2's A-reads need no barrier.
// mfma_f32_16x16x32_bf16; C/D: col=lane&15, row=(lane>>4)*4+reg  [m89/m91].
// ---------------------------------------------------------------------------
template <bool BN, bool TWO>
__global__ __launch_bounds__(256, 2) void layer_k(
    const ushort* __restrict__ A, const ushort* __restrict__ W1t,
    const float* __restrict__ bias1,
    const float* __restrict__ gamma, const float* __restrict__ beta,
    const float* __restrict__ mean, const float* __restrict__ var,
    const ushort* __restrict__ W2t, const float* __restrict__ bias2,
    ushort* __restrict__ O, int nrows)
{
    __shared__ ushort sA[16384];
    __shared__ ushort sW[16384];
    const int tid  = threadIdx.x;
    const int row0 = blockIdx.x * 128;

    // issue W2 loads early (consumed after GEMM1; latency fully hidden)
    short8 w2s[8];
    if (TWO) {
#pragma unroll
        for (int i = 0; i < 8; ++i)
            w2s[i] = ((const short8*)W2t)[i * 256 + tid];
    }

    // stage W1 (pre-swizzled -> linear copy)
    {
        const short8* srcv = (const short8*)W1t;
        short8* dstv = (short8*)sW;
#pragma unroll
        for (int i = 0; i < 8; ++i) dstv[i * 256 + tid] = srcv[i * 256 + tid];
    }
    // stage A with swizzle
#pragma unroll
    for (int i = 0; i < 8; ++i) {
        int f  = i * 256 + tid;     // 16B chunk id (2048 per tile)
        int r  = f >> 4;
        int c8 = f & 15;
        int gr = row0 + r;
        short8 v = {0, 0, 0, 0, 0, 0, 0, 0};
        if (gr < nrows) v = *(const short8*)(A + (size_t)gr * DD + c8 * 8);
        int db = (r * 256 + c8 * 16) ^ ((r & 7) << 4);
        *(short8*)((char*)sA + db) = v;
    }
    __syncthreads();

    const int lane = tid & 63;
    const int wv   = tid >> 6;
    const int m0   = wv * 32;
    const int lr   = lane & 15;
    const int lg   = lane >> 4;

    // epilogue-1 constants per col-frag: n = cf*16 + lr
    float mul8[8], add8[8];
#pragma unroll
    for (int cf = 0; cf < 8; ++cf) {
        int n = cf * 16 + lr;
        if (BN) {
            float s = gamma[n] * rsqrtf(var[n] + 1e-5f);
            mul8[cf] = s;
            add8[cf] = (bias1[n] - mean[n]) * s + beta[n];
        } else {
            mul8[cf] = 1.f;
            add8[cf] = bias1[n];
        }
    }

    f32x4 acc[2][8];
#pragma unroll
    for (int rf = 0; rf < 2; ++rf)
#pragma unroll
        for (int cf = 0; cf < 8; ++cf) acc[rf][cf] = (f32x4){0.f, 0.f, 0.f, 0.f};

    // ---- GEMM1: A @ W1 (both operands from LDS, swizzled) ----
#pragma unroll
    for (int kk = 0; kk < 4; ++kk) {
        const int kb = kk * 64 + lg * 16;          // byte offset of k-slice
        int ra0 = m0 + lr;
        int ra1 = m0 + 16 + lr;
        short8 a0 = *(short8*)((char*)sA + ((ra0 * 256 + kb) ^ ((ra0 & 7) << 4)));
        short8 a1 = *(short8*)((char*)sA + ((ra1 * 256 + kb) ^ ((ra1 & 7) << 4)));
        short8 b[8];
#pragma unroll
        for (int cf = 0; cf < 8; ++cf) {
            int rn = cf * 16 + lr;
            b[cf] = *(short8*)((char*)sW + ((rn * 256 + kb) ^ ((rn & 7) << 4)));
        }
#pragma unroll
        for (int cf = 0; cf < 8; ++cf) {
            acc[0][cf] = __builtin_amdgcn_mfma_f32_16x16x32_bf16(a0, b[cf], acc[0][cf], 0, 0, 0);
            acc[1][cf] = __builtin_amdgcn_mfma_f32_16x16x32_bf16(a1, b[cf], acc[1][cf], 0, 0, 0);
        }
    }

    if (!TWO) {
        // store epilogue-1 result
#pragma unroll
        for (int rf = 0; rf < 2; ++rf)
#pragma unroll
            for (int cf = 0; cf < 8; ++cf) {
                int n = cf * 16 + lr;
#pragma unroll
                for (int i = 0; i < 4; ++i) {
                    int m = row0 + m0 + rf * 16 + lg * 4 + i;
                    if (m < nrows) {
                        float vv = fmaxf(fmaf(acc[rf][cf][i], mul8[cf], add8[cf]), 0.f);
                        O[(size_t)m * DD + n] = (ushort)f2bf(vv);
                    }
                }
            }
        return;
    }

    // ---- epilogue-1 -> z (bf16) back into this wave's rows of sA ----
#pragma unroll
    for (int rf = 0; rf < 2; ++rf)
#pragma unroll
        for (int cf = 0; cf < 8; ++cf) {
            int n = cf * 16 + lr;
#pragma unroll
            for (int i = 0; i < 4; ++i) {
                int row = m0 + rf * 16 + lg * 4 + i;
                float vv = fmaxf(fmaf(acc[rf][cf][i], mul8[cf], add8[cf]), 0.f);
                int db = (row * 256 + n * 2) ^ ((row & 7) << 4);
                *(ushort*)((char*)sA + db) = (ushort)f2bf(vv);
            }
        }

    // ---- swap W1 -> W2 in sW (all waves must finish GEMM1's sW reads) ----
    __syncthreads();
    {
        short8* dstv = (short8*)sW;
#pragma unroll
        for (int i = 0; i < 8; ++i) dstv[i * 256 + tid] = w2s[i];
    }
    __syncthreads();

    // ---- GEMM2: z @ W2 (z's feature axis is the contraction axis ->
    //      identical swizzled A-frag reads; own-wave rows, no barrier) ----
    f32x4 acc2[2][8];
#pragma unroll
    for (int rf = 0; rf < 2; ++rf)
#pragma unroll
        for (int cf = 0; cf < 8; ++cf) acc2[rf][cf] = (f32x4){0.f, 0.f, 0.f, 0.f};

#pragma unroll
    for (int kk = 0; kk < 4; ++kk) {
        const int kb = kk * 64 + lg * 16;
        int ra0 = m0 + lr;
        int ra1 = m0 + 16 + lr;
        short8 a0 = *(short8*)((char*)sA + ((ra0 * 256 + kb) ^ ((ra0 & 7) << 4)));
        short8 a1 = *(short8*)((char*)sA + ((ra1 * 256 + kb) ^ ((ra1 & 7) << 4)));
        short8 b[8];
#pragma unroll
        for (int cf = 0; cf < 8; ++cf) {
            int rn = cf * 16 + lr;
            b[cf] = *(short8*)((char*)sW + ((rn * 256 + kb) ^ ((rn & 7) << 4)));
        }
#pragma unroll
        for (int cf = 0; cf < 8; ++cf) {
            acc2[0][cf] = __builtin_amdgcn_mfma_f32_16x16x32_bf16(a0, b[cf], acc2[0][cf], 0, 0, 0);
            acc2[1][cf] = __builtin_amdgcn_mfma_f32_16x16x32_bf16(a1, b[cf], acc2[1][cf], 0, 0, 0);
        }
    }

    // ---- epilogue-2: bias + relu, bf16 store ----
    float add2[8];
#pragma unroll
    for (int cf = 0; cf < 8; ++cf) add2[cf] = bias2[cf * 16 + lr];
#pragma unroll
    for (int rf = 0; rf < 2; ++rf)
#pragma unroll
        for (int cf = 0; cf < 8; ++cf) {
            int n = cf * 16 + lr;
#pragma unroll
            for (int i = 0; i < 4; ++i) {
                int m = row0 + m0 + rf * 16 + lg * 4 + i;
                if (m < nrows) {
                    float vv = fmaxf(acc2[rf][cf][i] + add2[cf], 0.f);
                    O[(size_t)m * DD + n] = (ushort)f2bf(vv);
                }
            }
        }
}

// ---------------------------------------------------------------------------
// lin2 (128 -> 10) + log_softmax, bf16 input. One wave per row.
// ---------------------------------------------------------------------------
__global__ __launch_bounds__(256) void lin2_lsm_k(
    const ushort* __restrict__ in, const float* __restrict__ w,
    const float* __restrict__ b, float* __restrict__ out, int n)
{
    int tid  = threadIdx.x;
    int lane = tid & 63;
    int row  = blockIdx.x * 4 + (tid >> 6);
    if (row >= n) return;

    const ushort* hr = in + (size_t)row * DD;
    float x0 = bf2f((short)hr[lane]);
    float x1 = bf2f((short)hr[lane + 64]);

    float p[10];
#pragma unroll
    for (int c = 0; c < 10; ++c)
        p[c] = fmaf(x0, w[lane * 10 + c], x1 * w[(lane + 64) * 10 + c]);

#pragma unroll
    for (int off = 32; off >= 1; off >>= 1) {
#pragma unroll
        for (int c = 0; c < 10; ++c) p[c] += __shfl_xor(p[c], off, 64);
    }
#pragma unroll
    for (int c = 0; c < 10; ++c) p[c] += b[c];

    float m = p[0];
#pragma unroll
    for (int c = 1; c < 10; ++c) m = fmaxf(m, p[c]);
    float s = 0.f;
#pragma unroll
    for (int c = 0; c < 10; ++c) s += expf(p[c] - m);
    float lse = m + logf(s);

    if (lane < 10) out[(size_t)row * 10 + lane] = p[lane] - lse;
}

// ---------------------------------------------------------------------------

extern "C" void kernel_launch(void* const* d_in, const int* in_sizes, int n_in,
                              void* d_out, int out_size, void* d_ws, size_t ws_size,
                              hipStream_t stream)
{
    const float* x      = (const float*)d_in[0];
    const int*   ei     = (const int*)d_in[1];
    const float* W1     = (const float*)d_in[2];
    const float* b1     = (const float*)d_in[3];
    const float* gamma  = (const float*)d_in[4];
    const float* beta   = (const float*)d_in[5];
    const float* mean   = (const float*)d_in[6];
    const float* var    = (const float*)d_in[7];
    const float* W2     = (const float*)d_in[8];
    const float* b2     = (const float*)d_in[9];
    const float* lin1_w = (const float*)d_in[10];
    const float* lin1_b = (const float*)d_in[11];
    const float* lin2_w = (const float*)d_in[12];
    const float* lin2_b = (const float*)d_in[13];

    const int N = in_sizes[0] / DD;
    const int E = in_sizes[1] / 2;
    const int* srcI = ei;
    const int* dstI = ei + E;

    // workspace layout (all 16B-aligned)
    ushort* hb     = (ushort*)d_ws;                 // N*128 bf16
    ushort* gb     = hb + (size_t)N * DD;           // N*128 bf16
    ushort* Wt     = gb + (size_t)N * DD;           // 11*16384 bf16 (swizzled)
    int*    rowptr = (int*)(Wt + 11 * 16384);       // N+4 ints
    int*    cnt    = rowptr + (N + 4);              // N ints (also cursor)
    int*    csr    = cnt + N;                       // E ints
    int*    bsum   = csr + E;                       // 128 ints

    const int nb       = (N + 1023) / 1024;
    const int gemmGrid = (N + 127) / 128;
    const int quadGrid = ((E + 3) / 4 + 255) / 256;

    // prep: bf16 conversions
    f2b_k<<<(N * DD / 8 + 255) / 256, 256, 0, stream>>>(x, hb, N * DD / 8);
    wconv_k<<<704, 256, 0, stream>>>(W1, W2, lin1_w, Wt);

    // CSR build
    hipMemsetAsync(cnt, 0, (size_t)N * sizeof(int), stream);
    hist_k<<<quadGrid, 256, 0, stream>>>(dstI, cnt, E);
    reduce_k<<<nb, 256, 0, stream>>>(cnt, bsum, N);
    scantop_k<<<1, 128, 0, stream>>>(bsum, rowptr + N, nb);
    scanapply_k<<<nb, 256, 0, stream>>>(cnt, bsum, rowptr, cnt, N);
    fill_k<<<quadGrid, 256, 0, stream>>>(srcI, dstI, cnt, csr, E);

    // layers: gather(hb->gb), fused layer (gb->hb)
    for (int l = 0; l < 5; ++l) {
        gather_bf_k<<<(N + 15) / 16, 256, 0, stream>>>(hb, rowptr, csr, gb, N);
        layer_k<true, true><<<gemmGrid, 256, 0, stream>>>(
            gb, Wt + (size_t)l * 16384, b1 + (size_t)l * DD,
            gamma + (size_t)l * DD, beta + (size_t)l * DD,
            mean + (size_t)l * DD, var + (size_t)l * DD,
            Wt + (size_t)(5 + l) * 16384, b2 + (size_t)l * DD, hb, N);
    }
    // lin1: hb -> gb
    layer_k<false, false><<<gemmGrid, 256, 0, stream>>>(
        hb, Wt + (size_t)10 * 16384, lin1_b,
        nullptr, nullptr, nullptr, nullptr, nullptr, nullptr, gb, N);
    // lin2 + log_softmax
    lin2_lsm_k<<<(N + 3) / 4, 256, 0, stream>>>(gb, lin2_w, lin2_b, (float*)d_out, N);
}

// Round 6
// 625.572 us; speedup vs baseline: 1.3583x; 1.1778x over previous
//
#include <hip/hip_runtime.h>
#include <hip/hip_bf16.h>

#define DD 128

typedef __attribute__((ext_vector_type(8))) short short8;
typedef __attribute__((ext_vector_type(4))) float f32x4;

__device__ __forceinline__ float bf2f(short s) {
    union { unsigned u; float f; } c; c.u = ((unsigned)(unsigned short)s) << 16; return c.f;
}
__device__ __forceinline__ short f2bf(float f) {   // round-to-nearest-even
    union { float f; unsigned u; } c; c.f = f;
    unsigned u = c.u + 0x7fffu + ((c.u >> 16) & 1u);
    return (short)(u >> 16);
}

// ---------------------------------------------------------------------------
// x (fp32) -> bf16
// ---------------------------------------------------------------------------
__global__ __launch_bounds__(256) void f2b_k(
    const float* __restrict__ x, ushort* __restrict__ o, int n8)
{
    int i = blockIdx.x * 256 + threadIdx.x;
    if (i < n8) {
        float4 v0 = ((const float4*)x)[(size_t)i * 2];
        float4 v1 = ((const float4*)x)[(size_t)i * 2 + 1];
        short8 r;
        r[0] = f2bf(v0.x); r[1] = f2bf(v0.y); r[2] = f2bf(v0.z); r[3] = f2bf(v0.w);
        r[4] = f2bf(v1.x); r[5] = f2bf(v1.y); r[6] = f2bf(v1.z); r[7] = f2bf(v1.w);
        ((short8*)o)[i] = r;
    }
}

// ---------------------------------------------------------------------------
// Weights: W[k][n] fp32 -> Wt[n][k] bf16, XOR-swizzled (ushort idx ^= (n&7)<<3)
// mats 0-4: W1 layers, 5-9: W2 layers, 10: lin1_w. 11*16384 elements.
// ---------------------------------------------------------------------------
__global__ __launch_bounds__(256) void wconv_k(
    const float* __restrict__ W1, const float* __restrict__ W2,
    const float* __restrict__ L1, ushort* __restrict__ Wt)
{
    int idx = blockIdx.x * 256 + threadIdx.x;
    int mat = idx >> 14;
    if (mat >= 11) return;
    int e = idx & 16383;
    int k = e >> 7, n = e & 127;
    const float* src = (mat < 5) ? (W1 + (size_t)mat * 16384)
                     : (mat < 10) ? (W2 + (size_t)(mat - 5) * 16384) : L1;
    float v = src[e];                       // e = k*128+n (coalesced read)
    int di = (n * 128 + k) ^ ((n & 7) << 3);
    Wt[(size_t)mat * 16384 + di] = (ushort)f2bf(v);
}

// lin2_w [128][10] fp32 -> L2t [16][128] bf16 (cols 10..15 zero-padded)
__global__ __launch_bounds__(256) void lin2conv_k(
    const float* __restrict__ w, ushort* __restrict__ L2t)
{
    int idx = blockIdx.x * 256 + threadIdx.x;
    if (idx >= 2048) return;
    int c = idx >> 7, k = idx & 127;
    float v = (c < 10) ? w[k * 10 + c] : 0.f;
    L2t[idx] = (ushort)f2bf(v);
}

// ---------------------------------------------------------------------------
// CSR build: histogram -> hierarchical exclusive scan -> fill
// ---------------------------------------------------------------------------
__global__ __launch_bounds__(256) void hist_k(
    const int* __restrict__ dst, int* __restrict__ cnt, int nEdges)
{
    int e0 = (blockIdx.x * 256 + threadIdx.x) * 4;
    if (e0 + 3 < nEdges) {
        int4 d = *(const int4*)(dst + e0);
        atomicAdd(&cnt[d.x], 1); atomicAdd(&cnt[d.y], 1);
        atomicAdd(&cnt[d.z], 1); atomicAdd(&cnt[d.w], 1);
    } else {
        for (int e = e0; e < nEdges; ++e) atomicAdd(&cnt[dst[e]], 1);
    }
}

__global__ __launch_bounds__(256) void reduce_k(
    const int* __restrict__ cnt, int* __restrict__ bsum, int n)
{
    __shared__ int s[256];
    int t = threadIdx.x;
    int base = blockIdx.x * 1024 + t * 4;
    int v = 0;
    if (base + 3 < n) { int4 c = *(const int4*)(cnt + base); v = c.x + c.y + c.z + c.w; }
    else { for (int i = 0; i < 4; ++i) if (base + i < n) v += cnt[base + i]; }
    s[t] = v; __syncthreads();
    for (int off = 128; off >= 1; off >>= 1) {
        if (t < off) s[t] += s[t + off];
        __syncthreads();
    }
    if (t == 0) bsum[blockIdx.x] = s[0];
}

__global__ __launch_bounds__(128) void scantop_k(
    int* __restrict__ bsum, int* __restrict__ totalOut, int nb)
{
    __shared__ int s[128];
    int t = threadIdx.x;
    int v = (t < nb) ? bsum[t] : 0;
    s[t] = v; __syncthreads();
    for (int off = 1; off < 128; off <<= 1) {
        int u = (t >= off) ? s[t - off] : 0;
        __syncthreads();
        s[t] += u;
        __syncthreads();
    }
    if (t < nb) bsum[t] = s[t] - v;       // exclusive
    if (t == 127) totalOut[0] = s[127];   // rowptr[N]
}

__global__ __launch_bounds__(256) void scanapply_k(
    const int* __restrict__ cnt, const int* __restrict__ bsum,
    int* __restrict__ rowptr, int* __restrict__ cursor, int n)
{
    __shared__ int s[256];
    int t = threadIdx.x;
    int base = blockIdx.x * 1024 + t * 4;
    int c[4]; int v = 0;
    for (int i = 0; i < 4; ++i) { c[i] = (base + i < n) ? cnt[base + i] : 0; v += c[i]; }
    s[t] = v; __syncthreads();
    int mine = v;
    for (int off = 1; off < 256; off <<= 1) {
        int u = (t >= off) ? s[t - off] : 0;
        __syncthreads();
        s[t] += u;
        __syncthreads();
    }
    int run = bsum[blockIdx.x] + s[t] - mine;
    for (int i = 0; i < 4; ++i) {
        if (base + i < n) { rowptr[base + i] = run; cursor[base + i] = run; run += c[i]; }
    }
}

// ---------------------------------------------------------------------------
// fill: XCD-local counting-sort scatter. Range r = blockIdx&7 (round-robin
// XCD heuristic): all csr writes for one contiguous ~800KB window come from
// one XCD -> lines fully populated in its L2 -> full-line writebacks.
// Each edge is read by 8 blocks, processed by exactly one (dst-range filter).
// Correct regardless of actual XCD mapping.
// ---------------------------------------------------------------------------
#define FILL_SUB 256
__global__ __launch_bounds__(256) void fill_k(
    const int* __restrict__ src, const int* __restrict__ dst,
    int* __restrict__ cursor, int* __restrict__ csr, int nEdges, int n)
{
    const int r    = blockIdx.x & 7;
    const int sub  = blockIdx.x >> 3;
    const int step = (n + 7) / 8;
    const int rlo  = r * step;
    const int rhi  = min(n, rlo + step);

    for (int base = sub * 1024; base < nEdges; base += FILL_SUB * 1024) {
        int e0 = base + threadIdx.x * 4;
        if (e0 + 3 < nEdges) {
            int4 d = *(const int4*)(dst + e0);
            int4 s = *(const int4*)(src + e0);
            if (d.x >= rlo && d.x < rhi) csr[atomicAdd(&cursor[d.x], 1)] = s.x;
            if (d.y >= rlo && d.y < rhi) csr[atomicAdd(&cursor[d.y], 1)] = s.y;
            if (d.z >= rlo && d.z < rhi) csr[atomicAdd(&cursor[d.z], 1)] = s.z;
            if (d.w >= rlo && d.w < rhi) csr[atomicAdd(&cursor[d.w], 1)] = s.w;
        } else {
            for (int e = e0; e < nEdges; ++e) {
                int d = dst[e];
                if (d >= rlo && d < rhi) csr[atomicAdd(&cursor[d], 1)] = src[e];
            }
        }
    }
}

// ---------------------------------------------------------------------------
// gather (bf16): out[i] = h[i] + sum_{k} h[csr[k]]   (fp32 accumulate)
// ---------------------------------------------------------------------------
__global__ __launch_bounds__(256) void gather_bf_k(
    const ushort* __restrict__ h, const int* __restrict__ rowptr,
    const int* __restrict__ csr, ushort* __restrict__ out, int n)
{
    int node = blockIdx.x * 16 + (threadIdx.x >> 4);
    int j = threadIdx.x & 15;
    if (node >= n) return;
    int beg = rowptr[node], end = rowptr[node + 1];
    const short8* hp = (const short8*)h;

    float a[8];
    short8 v = hp[(size_t)node * 16 + j];
#pragma unroll
    for (int i = 0; i < 8; ++i) a[i] = bf2f(v[i]);

    int k = beg;
    for (; k + 3 < end; k += 4) {
        int s0 = csr[k], s1 = csr[k + 1], s2 = csr[k + 2], s3 = csr[k + 3];
        short8 v0 = hp[(size_t)s0 * 16 + j];
        short8 v1 = hp[(size_t)s1 * 16 + j];
        short8 v2 = hp[(size_t)s2 * 16 + j];
        short8 v3 = hp[(size_t)s3 * 16 + j];
#pragma unroll
        for (int i = 0; i < 8; ++i)
            a[i] += (bf2f(v0[i]) + bf2f(v1[i])) + (bf2f(v2[i]) + bf2f(v3[i]));
    }
    for (; k < end; ++k) {
        int s0 = csr[k];
        short8 v0 = hp[(size_t)s0 * 16 + j];
#pragma unroll
        for (int i = 0; i < 8; ++i) a[i] += bf2f(v0[i]);
    }
    short8 r;
#pragma unroll
    for (int i = 0; i < 8; ++i) r[i] = f2bf(a[i]);
    ((short8*)out)[(size_t)node * 16 + j] = r;
}

// ---------------------------------------------------------------------------
// Fused layer.
// MODE 1: O(bf16) = relu( relu(BN(A@W1+b1)) @ W2 + b2 )
// MODE 2: OUT(f32) = log_softmax( relu(A@W1+b1) @ lin2 + lin2_b )
//   (W2t = L2t [16][128] bf16 zero-padded, bias2 = lin2_b)
// A bf16 [nrows][128]. W1t (and MODE1 W2t) transposed+pre-swizzled bf16.
// LDS: sA 32KB (XOR-swizzled byte^=(row&7)<<4) + sW 32KB.
// W2/L2t fetched into regs at entry (T14); z stays wave-private in sA.
// mfma_f32_16x16x32_bf16; C/D: col=lane&15, row=(lane>>4)*4+reg.
// ---------------------------------------------------------------------------
template <bool BN, int MODE>
__global__ __launch_bounds__(256, 2) void layer_k(
    const ushort* __restrict__ A, const ushort* __restrict__ W1t,
    const float* __restrict__ bias1,
    const float* __restrict__ gamma, const float* __restrict__ beta,
    const float* __restrict__ mean, const float* __restrict__ var,
    const ushort* __restrict__ W2t, const float* __restrict__ bias2,
    ushort* __restrict__ O, float* __restrict__ OUT, int nrows)
{
    __shared__ ushort sA[16384];
    __shared__ ushort sW[16384];
    const int tid  = threadIdx.x;
    const int row0 = blockIdx.x * 128;

    const int lane = tid & 63;
    const int wv   = tid >> 6;
    const int m0   = wv * 32;
    const int lr   = lane & 15;
    const int lg   = lane >> 4;

    // issue second-weight loads early (consumed after GEMM1; latency hidden)
    short8 w2s[8];
    short8 b2f[4];
    if (MODE == 1) {
#pragma unroll
        for (int i = 0; i < 8; ++i)
            w2s[i] = ((const short8*)W2t)[i * 256 + tid];
    } else {
#pragma unroll
        for (int kk = 0; kk < 4; ++kk)
            b2f[kk] = *(const short8*)(W2t + lr * 128 + kk * 32 + lg * 8);
    }

    // stage W1 (pre-swizzled -> linear copy)
    {
        const short8* srcv = (const short8*)W1t;
        short8* dstv = (short8*)sW;
#pragma unroll
        for (int i = 0; i < 8; ++i) dstv[i * 256 + tid] = srcv[i * 256 + tid];
    }
    // stage A with swizzle
#pragma unroll
    for (int i = 0; i < 8; ++i) {
        int f  = i * 256 + tid;
        int r  = f >> 4;
        int c8 = f & 15;
        int gr = row0 + r;
        short8 v = {0, 0, 0, 0, 0, 0, 0, 0};
        if (gr < nrows) v = *(const short8*)(A + (size_t)gr * DD + c8 * 8);
        int db = (r * 256 + c8 * 16) ^ ((r & 7) << 4);
        *(short8*)((char*)sA + db) = v;
    }
    __syncthreads();

    // epilogue-1 constants per col-frag: n = cf*16 + lr
    float mul8[8], add8[8];
#pragma unroll
    for (int cf = 0; cf < 8; ++cf) {
        int n = cf * 16 + lr;
        if (BN) {
            float s = gamma[n] * rsqrtf(var[n] + 1e-5f);
            mul8[cf] = s;
            add8[cf] = (bias1[n] - mean[n]) * s + beta[n];
        } else {
            mul8[cf] = 1.f;
            add8[cf] = bias1[n];
        }
    }

    f32x4 acc[2][8];
#pragma unroll
    for (int rf = 0; rf < 2; ++rf)
#pragma unroll
        for (int cf = 0; cf < 8; ++cf) acc[rf][cf] = (f32x4){0.f, 0.f, 0.f, 0.f};

    // ---- GEMM1: A @ W1 (both operands from LDS, swizzled) ----
#pragma unroll
    for (int kk = 0; kk < 4; ++kk) {
        const int kb = kk * 64 + lg * 16;
        int ra0 = m0 + lr;
        int ra1 = m0 + 16 + lr;
        short8 a0 = *(short8*)((char*)sA + ((ra0 * 256 + kb) ^ ((ra0 & 7) << 4)));
        short8 a1 = *(short8*)((char*)sA + ((ra1 * 256 + kb) ^ ((ra1 & 7) << 4)));
        short8 b[8];
#pragma unroll
        for (int cf = 0; cf < 8; ++cf) {
            int rn = cf * 16 + lr;
            b[cf] = *(short8*)((char*)sW + ((rn * 256 + kb) ^ ((rn & 7) << 4)));
        }
#pragma unroll
        for (int cf = 0; cf < 8; ++cf) {
            acc[0][cf] = __builtin_amdgcn_mfma_f32_16x16x32_bf16(a0, b[cf], acc[0][cf], 0, 0, 0);
            acc[1][cf] = __builtin_amdgcn_mfma_f32_16x16x32_bf16(a1, b[cf], acc[1][cf], 0, 0, 0);
        }
    }

    // ---- epilogue-1 -> z (bf16) back into this wave's rows of sA ----
#pragma unroll
    for (int rf = 0; rf < 2; ++rf)
#pragma unroll
        for (int cf = 0; cf < 8; ++cf) {
            int n = cf * 16 + lr;
#pragma unroll
            for (int i = 0; i < 4; ++i) {
                int row = m0 + rf * 16 + lg * 4 + i;
                float vv = fmaxf(fmaf(acc[rf][cf][i], mul8[cf], add8[cf]), 0.f);
                int db = (row * 256 + n * 2) ^ ((row & 7) << 4);
                *(ushort*)((char*)sA + db) = (ushort)f2bf(vv);
            }
        }

    if (MODE == 1) {
        // ---- swap W1 -> W2 in sW ----
        __syncthreads();
        {
            short8* dstv = (short8*)sW;
#pragma unroll
            for (int i = 0; i < 8; ++i) dstv[i * 256 + tid] = w2s[i];
        }
        __syncthreads();

        // ---- GEMM2: z @ W2 (own-wave rows of sA, no barrier) ----
        f32x4 acc2[2][8];
#pragma unroll
        for (int rf = 0; rf < 2; ++rf)
#pragma unroll
            for (int cf = 0; cf < 8; ++cf) acc2[rf][cf] = (f32x4){0.f, 0.f, 0.f, 0.f};

#pragma unroll
        for (int kk = 0; kk < 4; ++kk) {
            const int kb = kk * 64 + lg * 16;
            int ra0 = m0 + lr;
            int ra1 = m0 + 16 + lr;
            short8 a0 = *(short8*)((char*)sA + ((ra0 * 256 + kb) ^ ((ra0 & 7) << 4)));
            short8 a1 = *(short8*)((char*)sA + ((ra1 * 256 + kb) ^ ((ra1 & 7) << 4)));
            short8 b[8];
#pragma unroll
            for (int cf = 0; cf < 8; ++cf) {
                int rn = cf * 16 + lr;
                b[cf] = *(short8*)((char*)sW + ((rn * 256 + kb) ^ ((rn & 7) << 4)));
            }
#pragma unroll
            for (int cf = 0; cf < 8; ++cf) {
                acc2[0][cf] = __builtin_amdgcn_mfma_f32_16x16x32_bf16(a0, b[cf], acc2[0][cf], 0, 0, 0);
                acc2[1][cf] = __builtin_amdgcn_mfma_f32_16x16x32_bf16(a1, b[cf], acc2[1][cf], 0, 0, 0);
            }
        }

        float add2[8];
#pragma unroll
        for (int cf = 0; cf < 8; ++cf) add2[cf] = bias2[cf * 16 + lr];
#pragma unroll
        for (int rf = 0; rf < 2; ++rf)
#pragma unroll
            for (int cf = 0; cf < 8; ++cf) {
                int n = cf * 16 + lr;
#pragma unroll
                for (int i = 0; i < 4; ++i) {
                    int m = row0 + m0 + rf * 16 + lg * 4 + i;
                    if (m < nrows) {
                        float vv = fmaxf(acc2[rf][cf][i] + add2[cf], 0.f);
                        O[(size_t)m * DD + n] = (ushort)f2bf(vv);
                    }
                }
            }
    } else {
        // ---- lin2 (128->10 via padded 16-col MFMA) + log_softmax ----
        f32x4 acc2[2];
        acc2[0] = (f32x4){0.f, 0.f, 0.f, 0.f};
        acc2[1] = (f32x4){0.f, 0.f, 0.f, 0.f};
#pragma unroll
        for (int kk = 0; kk < 4; ++kk) {
            const int kb = kk * 64 + lg * 16;
            int ra0 = m0 + lr;
            int ra1 = m0 + 16 + lr;
            short8 a0 = *(short8*)((char*)sA + ((ra0 * 256 + kb) ^ ((ra0 & 7) << 4)));
            short8 a1 = *(short8*)((char*)sA + ((ra1 * 256 + kb) ^ ((ra1 & 7) << 4)));
            acc2[0] = __builtin_amdgcn_mfma_f32_16x16x32_bf16(a0, b2f[kk], acc2[0], 0, 0, 0);
            acc2[1] = __builtin_amdgcn_mfma_f32_16x16x32_bf16(a1, b2f[kk], acc2[1], 0, 0, 0);
        }
        float bc = (lr < 10) ? bias2[lr] : 0.f;
#pragma unroll
        for (int rf = 0; rf < 2; ++rf) {
#pragma unroll
            for (int i = 0; i < 4; ++i) {
                float p = (lr < 10) ? (acc2[rf][i] + bc) : -__builtin_inff();
                // max over the 16-lane group
                float m = p;
#pragma unroll
                for (int off = 8; off >= 1; off >>= 1)
                    m = fmaxf(m, __shfl_xor(m, off, 64));
                float e = expf(p - m);
#pragma unroll
                for (int off = 8; off >= 1; off >>= 1)
                    e += __shfl_xor(e, off, 64);
                float lse = m + logf(e);
                int grow = row0 + m0 + rf * 16 + lg * 4 + i;
                if (lr < 10 && grow < nrows)
                    OUT[(size_t)grow * 10 + lr] = p - lse;
            }
        }
    }
}

// ---------------------------------------------------------------------------

extern "C" void kernel_launch(void* const* d_in, const int* in_sizes, int n_in,
                              void* d_out, int out_size, void* d_ws, size_t ws_size,
                              hipStream_t stream)
{
    const float* x      = (const float*)d_in[0];
    const int*   ei     = (const int*)d_in[1];
    const float* W1     = (const float*)d_in[2];
    const float* b1     = (const float*)d_in[3];
    const float* gamma  = (const float*)d_in[4];
    const float* beta   = (const float*)d_in[5];
    const float* mean   = (const float*)d_in[6];
    const float* var    = (const float*)d_in[7];
    const float* W2     = (const float*)d_in[8];
    const float* b2     = (const float*)d_in[9];
    const float* lin1_w = (const float*)d_in[10];
    const float* lin1_b = (const float*)d_in[11];
    const float* lin2_w = (const float*)d_in[12];
    const float* lin2_b = (const float*)d_in[13];

    const int N = in_sizes[0] / DD;
    const int E = in_sizes[1] / 2;
    const int* srcI = ei;
    const int* dstI = ei + E;

    // workspace layout (all 16B-aligned)
    ushort* hb     = (ushort*)d_ws;                 // N*128 bf16
    ushort* gb     = hb + (size_t)N * DD;           // N*128 bf16
    ushort* Wt     = gb + (size_t)N * DD;           // 11*16384 bf16 (swizzled)
    ushort* L2t    = Wt + 11 * 16384;               // 16*128 bf16
    int*    rowptr = (int*)(L2t + 2048);            // N+4 ints
    int*    cnt    = rowptr + (N + 4);              // N ints (also cursor)
    int*    csr    = cnt + N;                       // E ints
    int*    bsum   = csr + E;                       // 128 ints

    const int nb       = (N + 1023) / 1024;
    const int gemmGrid = (N + 127) / 128;
    const int quadGrid = ((E + 3) / 4 + 255) / 256;

    // prep: bf16 conversions
    f2b_k<<<(N * DD / 8 + 255) / 256, 256, 0, stream>>>(x, hb, N * DD / 8);
    wconv_k<<<704, 256, 0, stream>>>(W1, W2, lin1_w, Wt);
    lin2conv_k<<<8, 256, 0, stream>>>(lin2_w, L2t);

    // CSR build
    hipMemsetAsync(cnt, 0, (size_t)N * sizeof(int), stream);
    hist_k<<<quadGrid, 256, 0, stream>>>(dstI, cnt, E);
    reduce_k<<<nb, 256, 0, stream>>>(cnt, bsum, N);
    scantop_k<<<1, 128, 0, stream>>>(bsum, rowptr + N, nb);
    scanapply_k<<<nb, 256, 0, stream>>>(cnt, bsum, rowptr, cnt, N);
    fill_k<<<8 * FILL_SUB, 256, 0, stream>>>(srcI, dstI, cnt, csr, E, N);

    // layers: gather(hb->gb), fused layer (gb->hb)
    for (int l = 0; l < 5; ++l) {
        gather_bf_k<<<(N + 15) / 16, 256, 0, stream>>>(hb, rowptr, csr, gb, N);
        layer_k<true, 1><<<gemmGrid, 256, 0, stream>>>(
            gb, Wt + (size_t)l * 16384, b1 + (size_t)l * DD,
            gamma + (size_t)l * DD, beta + (size_t)l * DD,
            mean + (size_t)l * DD, var + (size_t)l * DD,
            Wt + (size_t)(5 + l) * 16384, b2 + (size_t)l * DD, hb, nullptr, N);
    }
    // lin1 + lin2 + log_softmax fused: hb -> d_out
    layer_k<false, 2><<<gemmGrid, 256, 0, stream>>>(
        hb, Wt + (size_t)10 * 16384, lin1_b,
        nullptr, nullptr, nullptr, nullptr,
        L2t, lin2_b, nullptr, (float*)d_out, N);
}